// Round 22
// baseline (160.791 us; speedup 1.0000x reference)
//
#include <hip/hip_runtime.h>
#include <hip/hip_bf16.h>
#include <cstdint>

#define B_    256
#define S_    49
#define D_    448
#define H_    8
#define NTOK  (B_*S_)          // 12544 = 98*128
#define QKVO  1536
#define MLPH  1792
#define SCALE_ 0.17677669529663687f   // 32^-0.5

using bf16x8  = __attribute__((ext_vector_type(8))) __bf16;
using ushort8 = __attribute__((ext_vector_type(8))) unsigned short;
using f32x4   = __attribute__((ext_vector_type(4))) float;

__device__ __forceinline__ unsigned short f2bf(float f){
  uint32_t u = __builtin_bit_cast(uint32_t, f);
  u += 0x7fffu + ((u >> 16) & 1u);     // RNE
  return (unsigned short)(u >> 16);
}
__device__ __forceinline__ float b2f(unsigned short b){
  uint32_t u = ((uint32_t)b) << 16;
  return __builtin_bit_cast(float, u);
}

__device__ __forceinline__ void gload_lds16(const void* g, void* l){
  __builtin_amdgcn_global_load_lds(
      (const __attribute__((address_space(1))) void*)g,
      (__attribute__((address_space(3))) void*)l, 16, 0, 0);
}

// ---------- prep+ln fused: blocks <NTOK do LayerNorm, rest do weight prep ---
#define P_S0 688128L
#define P_S1 1490944L
#define P_S2 1949696L
#define P_S3 2752512L
#define P_S4 2932736L
#define P_S5 2936064L
#define P_S6 2936576L
#define P_S7 2969344L
#define PREP_BLKS 6628          // P_S7 / 448 exactly
__global__ __launch_bounds__(448)
void prepln_k(const float* __restrict__ x, const float* __restrict__ lw,
              const float* __restrict__ lb, unsigned short* __restrict__ normb,
              const float* __restrict__ qkvw, const float* __restrict__ fc1w,
              const float* __restrict__ projw, const float* __restrict__ fc2w,
              const float* __restrict__ ls1, const float* __restrict__ ls2,
              const float* __restrict__ qkvb, const float* __restrict__ fc1b,
              const float* __restrict__ projb, const float* __restrict__ fc2b,
              const float* __restrict__ attb, const int* __restrict__ idxs,
              unsigned short* __restrict__ wcat, unsigned short* __restrict__ wfused,
              float* __restrict__ cbig, float* __restrict__ cbv,
              float* __restrict__ biasf){
  const int bid = blockIdx.x, t = threadIdx.x;
  if (bid < NTOK){
    const float v = x[(size_t)bid*448 + t];
    float s1 = v, s2 = v*v;
    #pragma unroll
    for (int o = 32; o; o >>= 1){ s1 += __shfl_xor(s1, o); s2 += __shfl_xor(s2, o); }
    __shared__ float a1[7], a2[7];
    const int wid = t >> 6;
    if ((t & 63) == 0){ a1[wid] = s1; a2[wid] = s2; }
    __syncthreads();
    float S1 = 0.f, S2 = 0.f;
    #pragma unroll
    for (int i = 0; i < 7; ++i){ S1 += a1[i]; S2 += a2[i]; }
    const float mu  = S1 * (1.f/448.f);
    const float var = S2 * (1.f/448.f) - mu*mu;
    const float rs  = rsqrtf(var + 1e-12f);
    normb[(size_t)bid*448 + t] = f2bf((v - mu)*rs*lw[t] + lb[t]);
  } else {
    const long i = (long)(bid - NTOK)*448 + t;
    if (i < P_S0){
      wcat[i] = f2bf(qkvw[i]);
    } else if (i < P_S1){
      long j = i - P_S0;
      wcat[i] = f2bf(fc1w[j]);
    } else if (i < P_S2){
      long j = i - P_S1;
      long r = j / 1024;
      wfused[r*2816 + (j - r*1024)] = f2bf(projw[j]*ls1[r]);
    } else if (i < P_S3){
      long j = i - P_S2;
      long r = j / 1792;
      wfused[r*2816 + 1024 + (j - r*1792)] = f2bf(fc2w[j]*ls2[r]);
    } else if (i < P_S4){
      long j = i - P_S3;
      wfused[448L*2816 + j] = 0;
    } else if (i < P_S5){
      long j = i - P_S4;
      cbig[j] = (j < 1536) ? qkvb[j] : fc1b[j - 1536];
    } else if (i < P_S6){
      long j = i - P_S5;
      cbv[j] = (j < 448) ? ls1[j]*projb[j] + ls2[j]*fc2b[j] : 0.f;
    } else if (i < P_S7){
      long j = i - P_S6;
      int h = (int)(j >> 12), r = (int)((j >> 6) & 63), c = (int)(j & 63);
      float v;
      if (c >= 49) v = -1e30f;
      else { int q = r < 49 ? r : 48; v = attb[h*49 + idxs[q*49 + c]]; }
      biasf[j] = v;
    }
  }
}

// ---------- gemm4: QKV+FC1, BM=BN=128, BK=32, TRIPLE-buffered depth-2 -------
// R13 config + T5 setprio (R19 win). Paired-row LDS layout; stage(t+2) after
// barrier(t); counted vmcnt(4), vmcnt(0) last. T1 by-fast remap.
__global__ __launch_bounds__(256)
void gemm4_k(const unsigned short* __restrict__ A,
             const unsigned short* __restrict__ W,
             const float* __restrict__ bias,
             unsigned short* __restrict__ outB1,
             unsigned short* __restrict__ outB2,
             int splitBy, int nby)
{
  __shared__ char smem[65536];    // 3 bufs x 16KB; epilogue reuses 64KB

  const int NB = gridDim.x;
  const int q8 = NB >> 3, r8 = NB & 7;
  const int xcd = blockIdx.x & 7, idx = blockIdx.x >> 3;
  const int wgid = (xcd < r8 ? xcd*(q8+1) : r8*(q8+1) + (xcd-r8)*q8) + idx;
  const int bx = wgid / nby, by = wgid - bx*nby;

  const int t = threadIdx.x, lane = t & 63, wid = t >> 6;
  const int wm = wid >> 1, wn = wid & 1;
  const int g = lane >> 4, li = lane & 15;
  f32x4 acc[4][4] = {};

  const int l3   = lane >> 3;                 // dest line in chunk
  const int sp   = (lane & 7) ^ l3;           // logical slot
  const int rofs = 2*l3 + (sp >> 2);          // source row in chunk
  const int cofs = (sp & 3)*8;                // source k-offset (elems)

  auto stage = [&](int buf, int kt){
    char* Asb = smem + buf*16384;
    char* Bsb = Asb + 8192;
    const int k0 = kt*32;
    #pragma unroll
    for (int i = 0; i < 2; ++i){
      const int c = wid*2 + i;                // 8 chunks = 128 rows
      gload_lds16(A + (size_t)(bx*128 + c*16 + rofs)*448 + k0 + cofs, Asb + c*1024);
    }
    #pragma unroll
    for (int i = 0; i < 2; ++i){
      const int c = wid*2 + i;
      gload_lds16(W + (size_t)(by*128 + c*16 + rofs)*448 + k0 + cofs, Bsb + c*1024);
    }
  };

  const int sOff = (li >> 1)*128 + ((((li & 1)*4 + g) ^ (li >> 1)) << 4);

  stage(0, 0);
  stage(1, 1);
  int cur = 0, stg = 2;
  for (int kt = 0; kt < 14; ++kt){
    if (kt < 13) asm volatile("s_waitcnt vmcnt(4)" ::: "memory");
    else         asm volatile("s_waitcnt vmcnt(0)" ::: "memory");
    __builtin_amdgcn_s_barrier();
    if (kt + 2 < 14){ stage(stg, kt + 2); stg = (stg == 2) ? 0 : stg + 1; }
    char* Asb = smem + cur*16384;
    char* Bsb = Asb + 8192;
    bf16x8 af[4], bfr[4];
    #pragma unroll
    for (int mf = 0; mf < 4; ++mf)
      af[mf] = *reinterpret_cast<const bf16x8*>(Asb + (wm*4 + mf)*1024 + sOff);
    #pragma unroll
    for (int nf = 0; nf < 4; ++nf)
      bfr[nf] = *reinterpret_cast<const bf16x8*>(Bsb + (wn*4 + nf)*1024 + sOff);
    __builtin_amdgcn_s_setprio(1);            // T5
    #pragma unroll
    for (int mf = 0; mf < 4; ++mf)
      #pragma unroll
      for (int nf = 0; nf < 4; ++nf)
        acc[mf][nf] = __builtin_amdgcn_mfma_f32_16x16x32_bf16(af[mf], bfr[nf], acc[mf][nf], 0, 0, 0);
    __builtin_amdgcn_s_setprio(0);
    cur = (cur == 2) ? 0 : cur + 1;
  }
  __syncthreads();                            // reuse smem as f32 tile [128][128]

  const bool dogelu = by >= splitBy;
  #pragma unroll
  for (int mf = 0; mf < 4; ++mf){
    #pragma unroll
    for (int nf = 0; nf < 4; ++nf){
      const int col = wn*64 + nf*16 + li;
      const float bi = bias[by*128 + col];
      #pragma unroll
      for (int j = 0; j < 4; ++j){
        const int row = wm*64 + mf*16 + g*4 + j;
        float v = acc[mf][nf][j] + bi;
        if (dogelu) v = 0.5f*v*(1.0f + erff(v*0.70710678118654752f));
        *reinterpret_cast<float*>(smem + row*512 + ((col*4) ^ (((row >> 2) & 3) << 6))) = v;
      }
    }
  }
  __syncthreads();
  const int lr = lane >> 4, lc = lane & 15;
  #pragma unroll
  for (int it = 0; it < 8; ++it){
    const int r = wid*32 + it*4 + lr;
    const int sw = ((r >> 2) & 3) << 6;
    const f32x4 v0 = *reinterpret_cast<const f32x4*>(smem + r*512 + ((lc*32)      ^ sw));
    const f32x4 v1 = *reinterpret_cast<const f32x4*>(smem + r*512 + ((lc*32 + 16) ^ sw));
    ushort8 u;
    #pragma unroll
    for (int k = 0; k < 4; ++k){ u[k] = f2bf(v0[k]); u[4+k] = f2bf(v1[k]); }
    const int grow = bx*128 + r;
    if (by < splitBy)
      *reinterpret_cast<ushort8*>(outB1 + (size_t)grow*QKVO + by*128 + lc*8) = u;
    else
      *reinterpret_cast<ushort8*>(outB2 + (size_t)grow*MLPH + (by - splitBy)*128 + lc*8) = u;
  }
}

// ---------- gemm1: proj+FC2 fused, BK=64 TRIPLE-buffered depth-2 ------------
// gemm4's winning schedule at gemm1's proven BK=64 (44 barriers, 16 MFMA each
// — R13 showed BK=32's 88 barriers regress). 3 bufs: A 3x16KB + B 3x8KB =
// 72KB (2 blocks/CU; R9 showed gemm1 values pipeline depth > occupancy).
// stage(t+2) after barrier(t); counted vmcnt(6) (= one 6-load stage in
// flight), vmcnt(0) last; T5 setprio. T1 by-fast remap, T2 swizzle.
// out = resid + cbv + acc (weights pre-scaled by ls in prep).
__global__ __launch_bounds__(256)
void gemm1_k(const unsigned short* __restrict__ A1, int lda1, int nkt1,
             const unsigned short* __restrict__ A2, int lda2, int nkt,
             const unsigned short* __restrict__ W, int ldw,
             const float* __restrict__ bias,
             const float* __restrict__ resid, float* __restrict__ outF,
             int nby)
{
  __shared__ char smem[73728];   // A 3x16KB @0 | B 3x8KB @49152; epi reuses 32KB

  const int NB = gridDim.x;
  const int q8 = NB >> 3, r8 = NB & 7;
  const int xcd = blockIdx.x & 7, idx = blockIdx.x >> 3;
  const int wgid = (xcd < r8 ? xcd*(q8+1) : r8*(q8+1) + (xcd-r8)*q8) + idx;
  const int bx = wgid / nby, by = wgid - bx*nby;

  const int t = threadIdx.x, lane = t & 63, wid = t >> 6;
  const int wm = wid >> 1, wn = wid & 1;
  const int g = lane >> 4, li = lane & 15;
  f32x4 acc[4][2] = {};

  const int srow  = lane >> 3;
  const int scolw = ((lane & 7) ^ srow) * 8;

  auto stage = [&](int buf, int kt){
    char* Asb = smem + buf*16384;
    char* Bsb = smem + 49152 + buf*8192;
    const unsigned short* Ab; int lda, k0;
    if (kt < nkt1){ Ab = A1; lda = lda1; k0 = kt*64; }
    else          { Ab = A2; lda = lda2; k0 = (kt - nkt1)*64; }
    #pragma unroll
    for (int i = 0; i < 4; ++i){
      const int c = wid*4 + i;              // 16 chunks x 8 rows = 128 A-rows
      gload_lds16(Ab + (size_t)(bx*128 + c*8 + srow)*lda + k0 + scolw,
                  Asb + c*1024);
    }
    #pragma unroll
    for (int i = 0; i < 2; ++i){
      const int c = wid*2 + i;              // 8 chunks = 64 W-rows
      gload_lds16(W + (size_t)(by*64 + c*8 + srow)*ldw + kt*64 + scolw,
                  Bsb + c*1024);
    }
  };

  stage(0, 0);
  stage(1, 1);
  int cur = 0, stg = 2;
  for (int kt = 0; kt < nkt; ++kt){
    if (kt < nkt - 1) asm volatile("s_waitcnt vmcnt(6)" ::: "memory");
    else              asm volatile("s_waitcnt vmcnt(0)" ::: "memory");
    __builtin_amdgcn_s_barrier();
    if (kt + 2 < nkt){ stage(stg, kt + 2); stg = (stg == 2) ? 0 : stg + 1; }
    char* Asb = smem + cur*16384;
    char* Bsb = smem + 49152 + cur*8192;
    #pragma unroll
    for (int ks = 0; ks < 2; ++ks){
      const int kk2 = (ks*32 + g*8)*2;
      bf16x8 af[4], bfr[2];
      #pragma unroll
      for (int mf = 0; mf < 4; ++mf){
        const int row = wm*64 + mf*16 + li;
        af[mf] = *reinterpret_cast<const bf16x8*>(
            Asb + row*128 + (kk2 ^ ((row & 7) << 4)));
      }
      #pragma unroll
      for (int nf = 0; nf < 2; ++nf){
        const int row = wn*32 + nf*16 + li;
        bfr[nf] = *reinterpret_cast<const bf16x8*>(
            Bsb + row*128 + (kk2 ^ ((row & 7) << 4)));
      }
      __builtin_amdgcn_s_setprio(1);        // T5
      #pragma unroll
      for (int mf = 0; mf < 4; ++mf)
        #pragma unroll
        for (int nf = 0; nf < 2; ++nf)
          acc[mf][nf] = __builtin_amdgcn_mfma_f32_16x16x32_bf16(af[mf], bfr[nf], acc[mf][nf], 0, 0, 0);
      __builtin_amdgcn_s_setprio(0);
    }
    cur = (cur == 2) ? 0 : cur + 1;
  }
  __syncthreads();                          // reuse smem as [128][64] f32 tile

  const int lr = lane >> 4, lc = lane & 15;
  #pragma unroll
  for (int mf = 0; mf < 4; ++mf){
    #pragma unroll
    for (int nf = 0; nf < 2; ++nf){
      const int col = wn*32 + nf*16 + li;
      const float bi = bias[by*64 + col];
      #pragma unroll
      for (int j = 0; j < 4; ++j){
        const int rt = wm*64 + mf*16 + g*4 + j;
        *reinterpret_cast<float*>(smem + rt*256 + ((col*4) ^ (((rt >> 2) & 1) << 6)))
            = acc[mf][nf][j] + bi;
      }
    }
  }
  __syncthreads();
  #pragma unroll
  for (int i = 0; i < 8; ++i){
    const int r = wid*32 + i*4 + lr;
    const int sw = ((r >> 2) & 1) << 6;
    const f32x4 v = *reinterpret_cast<const f32x4*>(smem + r*256 + ((lc*16) ^ sw));
    const size_t o = (size_t)(bx*128 + r)*448 + by*64 + lc*4;
    const f32x4 rs = *reinterpret_cast<const f32x4*>(resid + o);
    *reinterpret_cast<f32x4*>(outF + o) = rs + v;
  }
}

// ---------- MFMA attention: one block (4 waves) per (b,h) -------------------
// Staging via global_load_lds (rule #21: linear LDS dest, pre-swizzled global
// source). Pad rows >=49: source row clamped to 48, then zero-filled after
// vmcnt(0) (full-row zeroing is swizzle-invariant).
__global__ __launch_bounds__(256)
void attn_mfma_k(const unsigned short* __restrict__ qkv,
                 const float* __restrict__ biasf,   // [8][64][64]
                 unsigned short* __restrict__ ctx)
{
  const int bh = blockIdx.x;
  const int b = bh >> 3, h = bh & 7;
  __shared__ unsigned short QKs[64*64];   //  8 KB: row k = [Q|K], slot s holds col s^(k&7)
  __shared__ unsigned short Vs[64*128];   // 16 KB, swizzled
  __shared__ unsigned short Ps[64*64];    //  8 KB, swizzled
  const int t = threadIdx.x, lane = t & 63, w = t >> 6;
  const int g = lane >> 4, li = lane & 15;
  const size_t qbase = ((size_t)b*49)*QKVO + (size_t)h*192;

  {
    const int kk = lane >> 3, ss = lane & 7;
    #pragma unroll
    for (int i = 0; i < 2; ++i){
      const int kb = (w*2 + i)*8;
      const int k  = kb + kk;
      const int ks = k < 49 ? k : 48;
      gload_lds16(qkv + qbase + (size_t)ks*QKVO + ((ss ^ (k & 7))*8),
                  (char*)QKs + kb*128);
    }
    const int kv = lane >> 4, sv = lane & 15;
    #pragma unroll
    for (int i = 0; i < 4; ++i){
      const int kb = (w*4 + i)*4;
      const int k  = kb + kv;
      const int ks = k < 49 ? k : 48;
      const int swz = (((unsigned)k >> 3) & 3) << 1;
      gload_lds16(qkv + qbase + 64 + (size_t)ks*QKVO + ((sv ^ swz)*8),
                  (char*)Vs + kb*256);
    }
  }
  asm volatile("s_waitcnt vmcnt(0)" ::: "memory");
  for (int e = t; e < 15*8; e += 256){
    const int k = 49 + (e >> 3), s = e & 7;
    *reinterpret_cast<bf16x8*>((char*)QKs + k*128 + s*16) = (bf16x8){};
  }
  for (int e = t; e < 15*16; e += 256){
    const int k = 49 + (e >> 4), s = e & 15;
    *reinterpret_cast<bf16x8*>((char*)Vs + k*256 + s*16) = (bf16x8){};
  }
  __syncthreads();

  const int qrow = w*16 + li;
  const bf16x8 afq = *reinterpret_cast<const bf16x8*>(
      (char*)QKs + qrow*128 + ((g ^ (qrow & 7)) << 4));
  f32x4 accs[4];
  #pragma unroll
  for (int nf = 0; nf < 4; ++nf){
    const int krow = nf*16 + li;
    const bf16x8 bfr = *reinterpret_cast<const bf16x8*>(
        (char*)QKs + krow*128 + (((4 + g) ^ (krow & 7)) << 4));
    f32x4 z = {};
    accs[nf] = __builtin_amdgcn_mfma_f32_16x16x32_bf16(afq, bfr, z, 0, 0, 0);
  }

  #pragma unroll
  for (int j = 0; j < 4; ++j){
    const int row = w*16 + g*4 + j;
    float sv[4];
    #pragma unroll
    for (int nf = 0; nf < 4; ++nf)
      sv[nf] = accs[nf][j]*SCALE_ + biasf[h*4096 + row*64 + nf*16 + li];
    float m = fmaxf(fmaxf(sv[0], sv[1]), fmaxf(sv[2], sv[3]));
    #pragma unroll
    for (int o = 8; o; o >>= 1) m = fmaxf(m, __shfl_xor(m, o));
    float e[4], s = 0.f;
    #pragma unroll
    for (int nf = 0; nf < 4; ++nf){ e[nf] = __expf(sv[nf] - m); s += e[nf]; }
    #pragma unroll
    for (int o = 8; o; o >>= 1) s += __shfl_xor(s, o);
    const float inv = 1.f / s;
    #pragma unroll
    for (int nf = 0; nf < 4; ++nf){
      const int byte = (row*128 + (nf*16 + li)*2) ^ ((row & 7) << 4);
      *reinterpret_cast<unsigned short*>((char*)Ps + byte) = f2bf(e[nf]*inv);
    }
  }
  __syncthreads();

  f32x4 accp[4][2] = {};
  #pragma unroll
  for (int kt = 0; kt < 2; ++kt){
    bf16x8 pa[4];
    #pragma unroll
    for (int mt = 0; mt < 4; ++mt){
      const int q = mt*16 + li;
      const int byte = (q*128 + kt*64 + g*16) ^ ((q & 7) << 4);
      pa[mt] = *reinterpret_cast<const bf16x8*>((char*)Ps + byte);
    }
    #pragma unroll
    for (int nf = 0; nf < 2; ++nf){
      const int d = w*32 + nf*16 + li;
      ushort8 vbu;
      #pragma unroll
      for (int j = 0; j < 8; ++j){
        const int k = kt*32 + g*8 + j;
        const int byte = (k*256 + d*2) ^ ((((unsigned)k >> 3) & 3) << 5);
        vbu[j] = *reinterpret_cast<const unsigned short*>((char*)Vs + byte);
      }
      const bf16x8 vb = __builtin_bit_cast(bf16x8, vbu);
      #pragma unroll
      for (int mt = 0; mt < 4; ++mt)
        accp[mt][nf] = __builtin_amdgcn_mfma_f32_16x16x32_bf16(pa[mt], vb, accp[mt][nf], 0, 0, 0);
    }
  }

  const size_t obase = ((size_t)b*49)*1024 + (size_t)h*128;
  #pragma unroll
  for (int mt = 0; mt < 4; ++mt){
    #pragma unroll
    for (int nf = 0; nf < 2; ++nf){
      #pragma unroll
      for (int j = 0; j < 4; ++j){
        const int row = mt*16 + g*4 + j;
        if (row < 49){
          const int col = w*32 + nf*16 + li;
          ctx[obase + (size_t)row*1024 + col] = f2bf(accp[mt][nf][j]);
        }
      }
    }
  }
}

// ---------------------------------------------------------------------------
extern "C" void kernel_launch(void* const* d_in, const int* in_sizes, int n_in,
                              void* d_out, int out_size, void* d_ws, size_t ws_size,
                              hipStream_t stream)
{
  const float* hidden = (const float*)d_in[0];
  const float* ln2w   = (const float*)d_in[1];
  const float* ln2b   = (const float*)d_in[2];
  const float* qkvw   = (const float*)d_in[3];
  const float* qkvb   = (const float*)d_in[4];
  const float* projw  = (const float*)d_in[5];
  const float* projb  = (const float*)d_in[6];
  const float* attb   = (const float*)d_in[7];
  const float* fc1w   = (const float*)d_in[8];
  const float* fc1b   = (const float*)d_in[9];
  const float* fc2w   = (const float*)d_in[10];
  const float* fc2b   = (const float*)d_in[11];
  const float* ls1    = (const float*)d_in[12];
  const float* ls2    = (const float*)d_in[13];
  const int*   aidx   = (const int*)d_in[14];
  float* out = (float*)d_out;

  char* p = (char*)d_ws;
  auto alloc = [&](size_t bytes){ void* r = (void*)p; p += (bytes + 255) & ~(size_t)255; return r; };
  unsigned short* wcat   = (unsigned short*)alloc((size_t)3328*448*2);  // [qkv;fc1]
  unsigned short* wfused = (unsigned short*)alloc((size_t)512*2816*2);  // [proj*ls1|fc2*ls2]
  unsigned short* normb  = (unsigned short*)alloc((size_t)NTOK*448*2);
  unsigned short* qkvv   = (unsigned short*)alloc((size_t)NTOK*QKVO*2);
  unsigned short* ctx    = (unsigned short*)alloc((size_t)NTOK*1024*2);
  unsigned short* hid    = (unsigned short*)alloc((size_t)NTOK*MLPH*2);
  float*          biasf  = (float*)alloc((size_t)8*64*64*4);
  float*          cbig   = (float*)alloc((size_t)3328*4);
  float*          cbv    = (float*)alloc((size_t)512*4);

  // fused prep + LayerNorm
  prepln_k<<<NTOK + PREP_BLKS, 448, 0, stream>>>(hidden, ln2w, ln2b, normb,
                                                 qkvw, fc1w, projw, fc2w, ls1, ls2,
                                                 qkvb, fc1b, projb, fc2b, attb, aidx,
                                                 wcat, wfused, cbig, cbv, biasf);

  // QKV+FC1: [12544,448] x [3328,448]^T; by<12 -> qkvv, else gelu -> hid
  gemm4_k<<<98*26, 256, 0, stream>>>(normb, wcat, cbig, qkvv, hid, 12, 26);
  // attention per (b,h), MFMA
  attn_mfma_k<<<B_*H_, 256, 0, stream>>>(qkvv, biasf, ctx);
  // fused proj+FC2: [ctx|hid] x wfused^T, out = hidden + cbv + acc
  gemm1_k<<<98*7, 256, 0, stream>>>(ctx, 1024, 16, hid, MLPH, 44,
                                    wfused, 2816, cbv,
                                    hidden, out, 7);
}

// Round 23
// 150.453 us; speedup vs baseline: 1.0687x; 1.0687x over previous
//
#include <hip/hip_runtime.h>
#include <hip/hip_bf16.h>
#include <cstdint>

#define B_    256
#define S_    49
#define D_    448
#define H_    8
#define NTOK  (B_*S_)          // 12544 = 98*128
#define QKVO  1536
#define MLPH  1792
#define SCALE_ 0.17677669529663687f   // 32^-0.5

using bf16x8  = __attribute__((ext_vector_type(8))) __bf16;
using ushort8 = __attribute__((ext_vector_type(8))) unsigned short;
using f32x4   = __attribute__((ext_vector_type(4))) float;

__device__ __forceinline__ unsigned short f2bf(float f){
  uint32_t u = __builtin_bit_cast(uint32_t, f);
  u += 0x7fffu + ((u >> 16) & 1u);     // RNE
  return (unsigned short)(u >> 16);
}
__device__ __forceinline__ float b2f(unsigned short b){
  uint32_t u = ((uint32_t)b) << 16;
  return __builtin_bit_cast(float, u);
}

__device__ __forceinline__ void gload_lds16(const void* g, void* l){
  __builtin_amdgcn_global_load_lds(
      (const __attribute__((address_space(1))) void*)g,
      (__attribute__((address_space(3))) void*)l, 16, 0, 0);
}

// ---------- prep+ln fused: blocks <NTOK do LayerNorm, rest do weight prep ---
#define P_S0 688128L
#define P_S1 1490944L
#define P_S2 1949696L
#define P_S3 2752512L
#define P_S4 2932736L
#define P_S5 2936064L
#define P_S6 2936576L
#define P_S7 2969344L
#define PREP_BLKS 6628          // P_S7 / 448 exactly
__global__ __launch_bounds__(448)
void prepln_k(const float* __restrict__ x, const float* __restrict__ lw,
              const float* __restrict__ lb, unsigned short* __restrict__ normb,
              const float* __restrict__ qkvw, const float* __restrict__ fc1w,
              const float* __restrict__ projw, const float* __restrict__ fc2w,
              const float* __restrict__ ls1, const float* __restrict__ ls2,
              const float* __restrict__ qkvb, const float* __restrict__ fc1b,
              const float* __restrict__ projb, const float* __restrict__ fc2b,
              const float* __restrict__ attb, const int* __restrict__ idxs,
              unsigned short* __restrict__ wcat, unsigned short* __restrict__ wfused,
              float* __restrict__ cbig, float* __restrict__ cbv,
              float* __restrict__ biasf){
  const int bid = blockIdx.x, t = threadIdx.x;
  if (bid < NTOK){
    const float v = x[(size_t)bid*448 + t];
    float s1 = v, s2 = v*v;
    #pragma unroll
    for (int o = 32; o; o >>= 1){ s1 += __shfl_xor(s1, o); s2 += __shfl_xor(s2, o); }
    __shared__ float a1[7], a2[7];
    const int wid = t >> 6;
    if ((t & 63) == 0){ a1[wid] = s1; a2[wid] = s2; }
    __syncthreads();
    float S1 = 0.f, S2 = 0.f;
    #pragma unroll
    for (int i = 0; i < 7; ++i){ S1 += a1[i]; S2 += a2[i]; }
    const float mu  = S1 * (1.f/448.f);
    const float var = S2 * (1.f/448.f) - mu*mu;
    const float rs  = rsqrtf(var + 1e-12f);
    normb[(size_t)bid*448 + t] = f2bf((v - mu)*rs*lw[t] + lb[t]);
  } else {
    const long i = (long)(bid - NTOK)*448 + t;
    if (i < P_S0){
      wcat[i] = f2bf(qkvw[i]);
    } else if (i < P_S1){
      long j = i - P_S0;
      wcat[i] = f2bf(fc1w[j]);
    } else if (i < P_S2){
      long j = i - P_S1;
      long r = j / 1024;
      wfused[r*2816 + (j - r*1024)] = f2bf(projw[j]*ls1[r]);
    } else if (i < P_S3){
      long j = i - P_S2;
      long r = j / 1792;
      wfused[r*2816 + 1024 + (j - r*1792)] = f2bf(fc2w[j]*ls2[r]);
    } else if (i < P_S4){
      long j = i - P_S3;
      wfused[448L*2816 + j] = 0;
    } else if (i < P_S5){
      long j = i - P_S4;
      cbig[j] = (j < 1536) ? qkvb[j] : fc1b[j - 1536];
    } else if (i < P_S6){
      long j = i - P_S5;
      cbv[j] = (j < 448) ? ls1[j]*projb[j] + ls2[j]*fc2b[j] : 0.f;
    } else if (i < P_S7){
      long j = i - P_S6;
      int h = (int)(j >> 12), r = (int)((j >> 6) & 63), c = (int)(j & 63);
      float v;
      if (c >= 49) v = -1e30f;
      else { int q = r < 49 ? r : 48; v = attb[h*49 + idxs[q*49 + c]]; }
      biasf[j] = v;
    }
  }
}

// ---------- gemm4: QKV+FC1, BM=BN=128, BK=32, TRIPLE-buffered depth-2 -------
// R13 config + T5 setprio (R19 win). Paired-row LDS layout; stage(t+2) after
// barrier(t); counted vmcnt(4), vmcnt(0) last. T1 by-fast remap.
__global__ __launch_bounds__(256)
void gemm4_k(const unsigned short* __restrict__ A,
             const unsigned short* __restrict__ W,
             const float* __restrict__ bias,
             unsigned short* __restrict__ outB1,
             unsigned short* __restrict__ outB2,
             int splitBy, int nby)
{
  __shared__ char smem[65536];    // 3 bufs x 16KB; epilogue reuses 64KB

  const int NB = gridDim.x;
  const int q8 = NB >> 3, r8 = NB & 7;
  const int xcd = blockIdx.x & 7, idx = blockIdx.x >> 3;
  const int wgid = (xcd < r8 ? xcd*(q8+1) : r8*(q8+1) + (xcd-r8)*q8) + idx;
  const int bx = wgid / nby, by = wgid - bx*nby;

  const int t = threadIdx.x, lane = t & 63, wid = t >> 6;
  const int wm = wid >> 1, wn = wid & 1;
  const int g = lane >> 4, li = lane & 15;
  f32x4 acc[4][4] = {};

  const int l3   = lane >> 3;                 // dest line in chunk
  const int sp   = (lane & 7) ^ l3;           // logical slot
  const int rofs = 2*l3 + (sp >> 2);          // source row in chunk
  const int cofs = (sp & 3)*8;                // source k-offset (elems)

  auto stage = [&](int buf, int kt){
    char* Asb = smem + buf*16384;
    char* Bsb = Asb + 8192;
    const int k0 = kt*32;
    #pragma unroll
    for (int i = 0; i < 2; ++i){
      const int c = wid*2 + i;                // 8 chunks = 128 rows
      gload_lds16(A + (size_t)(bx*128 + c*16 + rofs)*448 + k0 + cofs, Asb + c*1024);
    }
    #pragma unroll
    for (int i = 0; i < 2; ++i){
      const int c = wid*2 + i;
      gload_lds16(W + (size_t)(by*128 + c*16 + rofs)*448 + k0 + cofs, Bsb + c*1024);
    }
  };

  const int sOff = (li >> 1)*128 + ((((li & 1)*4 + g) ^ (li >> 1)) << 4);

  stage(0, 0);
  stage(1, 1);
  int cur = 0, stg = 2;
  for (int kt = 0; kt < 14; ++kt){
    if (kt < 13) asm volatile("s_waitcnt vmcnt(4)" ::: "memory");
    else         asm volatile("s_waitcnt vmcnt(0)" ::: "memory");
    __builtin_amdgcn_s_barrier();
    if (kt + 2 < 14){ stage(stg, kt + 2); stg = (stg == 2) ? 0 : stg + 1; }
    char* Asb = smem + cur*16384;
    char* Bsb = Asb + 8192;
    bf16x8 af[4], bfr[4];
    #pragma unroll
    for (int mf = 0; mf < 4; ++mf)
      af[mf] = *reinterpret_cast<const bf16x8*>(Asb + (wm*4 + mf)*1024 + sOff);
    #pragma unroll
    for (int nf = 0; nf < 4; ++nf)
      bfr[nf] = *reinterpret_cast<const bf16x8*>(Bsb + (wn*4 + nf)*1024 + sOff);
    __builtin_amdgcn_s_setprio(1);            // T5
    #pragma unroll
    for (int mf = 0; mf < 4; ++mf)
      #pragma unroll
      for (int nf = 0; nf < 4; ++nf)
        acc[mf][nf] = __builtin_amdgcn_mfma_f32_16x16x32_bf16(af[mf], bfr[nf], acc[mf][nf], 0, 0, 0);
    __builtin_amdgcn_s_setprio(0);
    cur = (cur == 2) ? 0 : cur + 1;
  }
  __syncthreads();                            // reuse smem as f32 tile [128][128]

  const bool dogelu = by >= splitBy;
  #pragma unroll
  for (int mf = 0; mf < 4; ++mf){
    #pragma unroll
    for (int nf = 0; nf < 4; ++nf){
      const int col = wn*64 + nf*16 + li;
      const float bi = bias[by*128 + col];
      #pragma unroll
      for (int j = 0; j < 4; ++j){
        const int row = wm*64 + mf*16 + g*4 + j;
        float v = acc[mf][nf][j] + bi;
        if (dogelu) v = 0.5f*v*(1.0f + erff(v*0.70710678118654752f));
        *reinterpret_cast<float*>(smem + row*512 + ((col*4) ^ (((row >> 2) & 3) << 6))) = v;
      }
    }
  }
  __syncthreads();
  const int lr = lane >> 4, lc = lane & 15;
  #pragma unroll
  for (int it = 0; it < 8; ++it){
    const int r = wid*32 + it*4 + lr;
    const int sw = ((r >> 2) & 3) << 6;
    const f32x4 v0 = *reinterpret_cast<const f32x4*>(smem + r*512 + ((lc*32)      ^ sw));
    const f32x4 v1 = *reinterpret_cast<const f32x4*>(smem + r*512 + ((lc*32 + 16) ^ sw));
    ushort8 u;
    #pragma unroll
    for (int k = 0; k < 4; ++k){ u[k] = f2bf(v0[k]); u[4+k] = f2bf(v1[k]); }
    const int grow = bx*128 + r;
    if (by < splitBy)
      *reinterpret_cast<ushort8*>(outB1 + (size_t)grow*QKVO + by*128 + lc*8) = u;
    else
      *reinterpret_cast<ushort8*>(outB2 + (size_t)grow*MLPH + (by - splitBy)*128 + lc*8) = u;
  }
}

// ---------- gemm1: proj+FC2 fused (R10/R21 structure — best measured) -------
// BM=128, BN=64, BK=64, 4 waves, dbuf 48KB, one barrier/K-tile, T1+T2.
// out = resid + cbv + acc (weights pre-scaled by ls in prep).
__global__ __launch_bounds__(256)
void gemm1_k(const unsigned short* __restrict__ A1, int lda1, int nkt1,
             const unsigned short* __restrict__ A2, int lda2, int nkt,
             const unsigned short* __restrict__ W, int ldw,
             const float* __restrict__ bias,
             const float* __restrict__ resid, float* __restrict__ outF,
             int nby)
{
  constexpr int BN = 64, NF = 2;
  __shared__ char smem[49152];

  const int NB = gridDim.x;
  const int q8 = NB >> 3, r8 = NB & 7;
  const int xcd = blockIdx.x & 7, idx = blockIdx.x >> 3;
  const int wgid = (xcd < r8 ? xcd*(q8+1) : r8*(q8+1) + (xcd-r8)*q8) + idx;
  const int bx = wgid / nby, by = wgid - bx*nby;

  const int t = threadIdx.x, lane = t & 63, wid = t >> 6;
  const int wm = wid >> 1, wn = wid & 1;
  const int g = lane >> 4, li = lane & 15;
  f32x4 acc[4][NF] = {};

  const int srow  = lane >> 3;
  const int scolw = ((lane & 7) ^ srow) * 8;

  auto stage = [&](int buf, int kt){
    char* Asb = smem + buf*16384;
    char* Bsb = smem + 32768 + buf*(BN*128);
    const unsigned short* Ab; int lda, k0;
    if (kt < nkt1){ Ab = A1; lda = lda1; k0 = kt*64; }
    else          { Ab = A2; lda = lda2; k0 = (kt - nkt1)*64; }
    #pragma unroll
    for (int i = 0; i < 4; ++i){
      const int c = wid*4 + i;
      gload_lds16(Ab + (size_t)(bx*128 + c*8 + srow)*lda + k0 + scolw,
                  Asb + c*1024);
    }
    #pragma unroll
    for (int i = 0; i < NF; ++i){
      const int c = wid*NF + i;
      gload_lds16(W + (size_t)(by*BN + c*8 + srow)*ldw + kt*64 + scolw,
                  Bsb + c*1024);
    }
  };

  int buf = 0;
  stage(0, 0);
  for (int kt = 0; kt < nkt; ++kt){
    __syncthreads();
    if (kt + 1 < nkt) stage(buf ^ 1, kt + 1);
    char* Asb = smem + buf*16384;
    char* Bsb = smem + 32768 + buf*(BN*128);
    #pragma unroll
    for (int ks = 0; ks < 2; ++ks){
      const int kk2 = (ks*32 + g*8)*2;
      bf16x8 af[4], bfr[NF];
      #pragma unroll
      for (int mf = 0; mf < 4; ++mf){
        const int row = wm*64 + mf*16 + li;
        af[mf] = *reinterpret_cast<const bf16x8*>(
            Asb + row*128 + (kk2 ^ ((row & 7) << 4)));
      }
      #pragma unroll
      for (int nf = 0; nf < NF; ++nf){
        const int row = wn*(BN/2) + nf*16 + li;
        bfr[nf] = *reinterpret_cast<const bf16x8*>(
            Bsb + row*128 + (kk2 ^ ((row & 7) << 4)));
      }
      #pragma unroll
      for (int mf = 0; mf < 4; ++mf)
        #pragma unroll
        for (int nf = 0; nf < NF; ++nf)
          acc[mf][nf] = __builtin_amdgcn_mfma_f32_16x16x32_bf16(af[mf], bfr[nf], acc[mf][nf], 0, 0, 0);
    }
    buf ^= 1;
  }
  __syncthreads();

  const int lr = lane >> 4, lc = lane & 15;
  #pragma unroll
  for (int mf = 0; mf < 4; ++mf){
    #pragma unroll
    for (int nf = 0; nf < NF; ++nf){
      const int col = wn*32 + nf*16 + li;
      const float bi = bias[by*64 + col];
      #pragma unroll
      for (int j = 0; j < 4; ++j){
        const int rt = wm*64 + mf*16 + g*4 + j;
        *reinterpret_cast<float*>(smem + rt*256 + ((col*4) ^ (((rt >> 2) & 1) << 6)))
            = acc[mf][nf][j] + bi;
      }
    }
  }
  __syncthreads();
  #pragma unroll
  for (int i = 0; i < 8; ++i){
    const int r = wid*32 + i*4 + lr;
    const int sw = ((r >> 2) & 1) << 6;
    const f32x4 v = *reinterpret_cast<const f32x4*>(smem + r*256 + ((lc*16) ^ sw));
    const size_t o = (size_t)(bx*128 + r)*448 + by*64 + lc*4;
    const f32x4 rs = *reinterpret_cast<const f32x4*>(resid + o);
    *reinterpret_cast<f32x4*>(outF + o) = rs + v;
  }
}

// ---------- MFMA attention: one block (4 waves) per (b,h) -------------------
// Staging via global_load_lds (rule #21: linear LDS dest, pre-swizzled global
// source). Pad rows >=49: source row clamped to 48, then zero-filled after
// vmcnt(0) (full-row zeroing is swizzle-invariant).
__global__ __launch_bounds__(256)
void attn_mfma_k(const unsigned short* __restrict__ qkv,
                 const float* __restrict__ biasf,   // [8][64][64]
                 unsigned short* __restrict__ ctx)
{
  const int bh = blockIdx.x;
  const int b = bh >> 3, h = bh & 7;
  __shared__ unsigned short QKs[64*64];   //  8 KB: row k = [Q|K], slot s holds col s^(k&7)
  __shared__ unsigned short Vs[64*128];   // 16 KB, swizzled
  __shared__ unsigned short Ps[64*64];    //  8 KB, swizzled
  const int t = threadIdx.x, lane = t & 63, w = t >> 6;
  const int g = lane >> 4, li = lane & 15;
  const size_t qbase = ((size_t)b*49)*QKVO + (size_t)h*192;

  {
    const int kk = lane >> 3, ss = lane & 7;
    #pragma unroll
    for (int i = 0; i < 2; ++i){
      const int kb = (w*2 + i)*8;
      const int k  = kb + kk;
      const int ks = k < 49 ? k : 48;
      gload_lds16(qkv + qbase + (size_t)ks*QKVO + ((ss ^ (k & 7))*8),
                  (char*)QKs + kb*128);
    }
    const int kv = lane >> 4, sv = lane & 15;
    #pragma unroll
    for (int i = 0; i < 4; ++i){
      const int kb = (w*4 + i)*4;
      const int k  = kb + kv;
      const int ks = k < 49 ? k : 48;
      const int swz = (((unsigned)k >> 3) & 3) << 1;
      gload_lds16(qkv + qbase + 64 + (size_t)ks*QKVO + ((sv ^ swz)*8),
                  (char*)Vs + kb*256);
    }
  }
  asm volatile("s_waitcnt vmcnt(0)" ::: "memory");
  for (int e = t; e < 15*8; e += 256){
    const int k = 49 + (e >> 3), s = e & 7;
    *reinterpret_cast<bf16x8*>((char*)QKs + k*128 + s*16) = (bf16x8){};
  }
  for (int e = t; e < 15*16; e += 256){
    const int k = 49 + (e >> 4), s = e & 15;
    *reinterpret_cast<bf16x8*>((char*)Vs + k*256 + s*16) = (bf16x8){};
  }
  __syncthreads();

  const int qrow = w*16 + li;
  const bf16x8 afq = *reinterpret_cast<const bf16x8*>(
      (char*)QKs + qrow*128 + ((g ^ (qrow & 7)) << 4));
  f32x4 accs[4];
  #pragma unroll
  for (int nf = 0; nf < 4; ++nf){
    const int krow = nf*16 + li;
    const bf16x8 bfr = *reinterpret_cast<const bf16x8*>(
        (char*)QKs + krow*128 + (((4 + g) ^ (krow & 7)) << 4));
    f32x4 z = {};
    accs[nf] = __builtin_amdgcn_mfma_f32_16x16x32_bf16(afq, bfr, z, 0, 0, 0);
  }

  #pragma unroll
  for (int j = 0; j < 4; ++j){
    const int row = w*16 + g*4 + j;
    float sv[4];
    #pragma unroll
    for (int nf = 0; nf < 4; ++nf)
      sv[nf] = accs[nf][j]*SCALE_ + biasf[h*4096 + row*64 + nf*16 + li];
    float m = fmaxf(fmaxf(sv[0], sv[1]), fmaxf(sv[2], sv[3]));
    #pragma unroll
    for (int o = 8; o; o >>= 1) m = fmaxf(m, __shfl_xor(m, o));
    float e[4], s = 0.f;
    #pragma unroll
    for (int nf = 0; nf < 4; ++nf){ e[nf] = __expf(sv[nf] - m); s += e[nf]; }
    #pragma unroll
    for (int o = 8; o; o >>= 1) s += __shfl_xor(s, o);
    const float inv = 1.f / s;
    #pragma unroll
    for (int nf = 0; nf < 4; ++nf){
      const int byte = (row*128 + (nf*16 + li)*2) ^ ((row & 7) << 4);
      *reinterpret_cast<unsigned short*>((char*)Ps + byte) = f2bf(e[nf]*inv);
    }
  }
  __syncthreads();

  f32x4 accp[4][2] = {};
  #pragma unroll
  for (int kt = 0; kt < 2; ++kt){
    bf16x8 pa[4];
    #pragma unroll
    for (int mt = 0; mt < 4; ++mt){
      const int q = mt*16 + li;
      const int byte = (q*128 + kt*64 + g*16) ^ ((q & 7) << 4);
      pa[mt] = *reinterpret_cast<const bf16x8*>((char*)Ps + byte);
    }
    #pragma unroll
    for (int nf = 0; nf < 2; ++nf){
      const int d = w*32 + nf*16 + li;
      ushort8 vbu;
      #pragma unroll
      for (int j = 0; j < 8; ++j){
        const int k = kt*32 + g*8 + j;
        const int byte = (k*256 + d*2) ^ ((((unsigned)k >> 3) & 3) << 5);
        vbu[j] = *reinterpret_cast<const unsigned short*>((char*)Vs + byte);
      }
      const bf16x8 vb = __builtin_bit_cast(bf16x8, vbu);
      #pragma unroll
      for (int mt = 0; mt < 4; ++mt)
        accp[mt][nf] = __builtin_amdgcn_mfma_f32_16x16x32_bf16(pa[mt], vb, accp[mt][nf], 0, 0, 0);
    }
  }

  const size_t obase = ((size_t)b*49)*1024 + (size_t)h*128;
  #pragma unroll
  for (int mt = 0; mt < 4; ++mt){
    #pragma unroll
    for (int nf = 0; nf < 2; ++nf){
      #pragma unroll
      for (int j = 0; j < 4; ++j){
        const int row = mt*16 + g*4 + j;
        if (row < 49){
          const int col = w*32 + nf*16 + li;
          ctx[obase + (size_t)row*1024 + col] = f2bf(accp[mt][nf][j]);
        }
      }
    }
  }
}

// ---------------------------------------------------------------------------
extern "C" void kernel_launch(void* const* d_in, const int* in_sizes, int n_in,
                              void* d_out, int out_size, void* d_ws, size_t ws_size,
                              hipStream_t stream)
{
  const float* hidden = (const float*)d_in[0];
  const float* ln2w   = (const float*)d_in[1];
  const float* ln2b   = (const float*)d_in[2];
  const float* qkvw   = (const float*)d_in[3];
  const float* qkvb   = (const float*)d_in[4];
  const float* projw  = (const float*)d_in[5];
  const float* projb  = (const float*)d_in[6];
  const float* attb   = (const float*)d_in[7];
  const float* fc1w   = (const float*)d_in[8];
  const float* fc1b   = (const float*)d_in[9];
  const float* fc2w   = (const float*)d_in[10];
  const float* fc2b   = (const float*)d_in[11];
  const float* ls1    = (const float*)d_in[12];
  const float* ls2    = (const float*)d_in[13];
  const int*   aidx   = (const int*)d_in[14];
  float* out = (float*)d_out;

  char* p = (char*)d_ws;
  auto alloc = [&](size_t bytes){ void* r = (void*)p; p += (bytes + 255) & ~(size_t)255; return r; };
  unsigned short* wcat   = (unsigned short*)alloc((size_t)3328*448*2);  // [qkv;fc1]
  unsigned short* wfused = (unsigned short*)alloc((size_t)512*2816*2);  // [proj*ls1|fc2*ls2]
  unsigned short* normb  = (unsigned short*)alloc((size_t)NTOK*448*2);
  unsigned short* qkvv   = (unsigned short*)alloc((size_t)NTOK*QKVO*2);
  unsigned short* ctx    = (unsigned short*)alloc((size_t)NTOK*1024*2);
  unsigned short* hid    = (unsigned short*)alloc((size_t)NTOK*MLPH*2);
  float*          biasf  = (float*)alloc((size_t)8*64*64*4);
  float*          cbig   = (float*)alloc((size_t)3328*4);
  float*          cbv    = (float*)alloc((size_t)512*4);

  // fused prep + LayerNorm
  prepln_k<<<NTOK + PREP_BLKS, 448, 0, stream>>>(hidden, ln2w, ln2b, normb,
                                                 qkvw, fc1w, projw, fc2w, ls1, ls2,
                                                 qkvb, fc1b, projb, fc2b, attb, aidx,
                                                 wcat, wfused, cbig, cbv, biasf);

  // QKV+FC1: [12544,448] x [3328,448]^T; by<12 -> qkvv, else gelu -> hid
  gemm4_k<<<98*26, 256, 0, stream>>>(normb, wcat, cbig, qkvv, hid, 12, 26);
  // attention per (b,h), MFMA
  attn_mfma_k<<<B_*H_, 256, 0, stream>>>(qkvv, biasf, ctx);
  // fused proj+FC2: [ctx|hid] x wfused^T, out = hidden + cbv + acc
  gemm1_k<<<98*7, 256, 0, stream>>>(ctx, 1024, 16, hid, MLPH, 44,
                                    wfused, 2816, cbv,
                                    hidden, out, 7);
}